// Round 8
// baseline (354.237 us; speedup 1.0000x reference)
//
#include <hip/hip_runtime.h>

// out[i] = sum_{e: rows[e]==i} Param_W[params[e]] * x[cols[e]] + Param_b[b_params[i]]
// N = 262144, E = 16777216, NPARAMS = 1280, NB = 16.
//
// Measured HW model: LDS ds_add_f32 ~3.1 cyc per ACTIVE lane (R5/R6) -> scan
// floor ~85 us for E adds over 256 CUs. R6: scan=109, val=88, reduce=7,
// harness fixed ~130. R7b: register double-buffered scan (overlap VMEM loads
// with DS atomics) + deeper-MLP val kernel (VB=8, nontemporal index streams
// via clang ext_vector_type — HIP_vector_type is rejected by the builtin).

#define SLICE_BITS  15
#define SLICE_SIZE  (1 << SLICE_BITS)   // 32768
#define SLICES      8
#define CHUNKS      32
#define NPARAMS_MAX 2048
#define SCAN_THREADS 1024
#define SB4         4                   // int4-groups per ping-pong buffer
#define VB          8                   // batched groups per val-kernel thread

typedef int v4i __attribute__((ext_vector_type(4)));

// ---------------- Kernel V: val precompute (streaming) ----------------
__global__ __launch_bounds__(256) void val_kernel(
    const float* __restrict__ x, const float* __restrict__ PW, int nparams,
    const v4i* __restrict__ cols4, const v4i* __restrict__ params4,
    float4* __restrict__ vals4)
{
    __shared__ float pw[NPARAMS_MAX];
    for (int j = threadIdx.x; j < nparams; j += 256) pw[j] = PW[j];
    __syncthreads();
    const int base = blockIdx.x * (256 * VB) + threadIdx.x;
    v4i c[VB], p[VB];
#pragma unroll
    for (int k = 0; k < VB; ++k) {
        c[k] = __builtin_nontemporal_load(&cols4[base + k * 256]);   // read-once stream
        p[k] = __builtin_nontemporal_load(&params4[base + k * 256]);
    }
#pragma unroll
    for (int k = 0; k < VB; ++k) {
        float4 v;
        v.x = pw[p[k].x] * x[c[k].x];
        v.y = pw[p[k].y] * x[c[k].y];
        v.z = pw[p[k].z] * x[c[k].z];
        v.w = pw[p[k].w] * x[c[k].w];
        vals4[base + k * 256] = v;      // cached store: scan re-reads from L3
    }
}

// ------- Kernel S: 2-stream scan, ping-pong prefetch + predicated adds -------
__global__ __launch_bounds__(SCAN_THREADS, 1) void scan4_kernel(
    const int4* __restrict__ rows4, const float4* __restrict__ vals4,
    float* __restrict__ partials, int e4_per_chunk)
{
    __shared__ float acc[SLICE_SIZE];    // 128 KiB -> 1 block/CU
    const int bid = blockIdx.x;
    const int s = bid / CHUNKS;          // slice
    const int c = bid % CHUNKS;          // chunk; bid%8 == c%8 -> the 8 readers of a
                                         // chunk co-locate on one XCD (round-robin)
    for (int j = threadIdx.x; j < SLICE_SIZE; j += SCAN_THREADS) acc[j] = 0.0f;
    __syncthreads();

    const int4*   rp = rows4 + (size_t)c * e4_per_chunk;
    const float4* vp = vals4 + (size_t)c * e4_per_chunk;
    const int per_thread = e4_per_chunk / SCAN_THREADS;   // 128

    int4   rA[SB4], rB[SB4];
    float4 vA[SB4], vB[SB4];

#define LOAD(dstR, dstV, b0)                                             \
    _Pragma("unroll")                                                    \
    for (int b = 0; b < SB4; ++b) {                                      \
        const int g = ((b0) + b) * SCAN_THREADS + threadIdx.x;           \
        dstR[b] = rp[g];                                                 \
        dstV[b] = vp[g];                                                 \
    }
#define PROC(rX, vX)                                                     \
    _Pragma("unroll")                                                    \
    for (int b = 0; b < SB4; ++b) {                                      \
        if ((rX[b].x >> SLICE_BITS) == s) atomicAdd(&acc[rX[b].x & (SLICE_SIZE - 1)], vX[b].x); \
        if ((rX[b].y >> SLICE_BITS) == s) atomicAdd(&acc[rX[b].y & (SLICE_SIZE - 1)], vX[b].y); \
        if ((rX[b].z >> SLICE_BITS) == s) atomicAdd(&acc[rX[b].z & (SLICE_SIZE - 1)], vX[b].z); \
        if ((rX[b].w >> SLICE_BITS) == s) atomicAdd(&acc[rX[b].w & (SLICE_SIZE - 1)], vX[b].w); \
    }

    LOAD(rA, vA, 0)
    for (int base = 0; base < per_thread; base += 2 * SB4) {
        LOAD(rB, vB, base + SB4)           // in flight while A's atomics issue
        PROC(rA, vA)
        if (base + 2 * SB4 < per_thread) {
            LOAD(rA, vA, base + 2 * SB4)   // in flight while B's atomics issue
        }
        PROC(rB, vB)
    }
#undef LOAD
#undef PROC
    __syncthreads();

    float* dst = partials + (size_t)bid * SLICE_SIZE;
    for (int j = threadIdx.x; j < SLICE_SIZE; j += SCAN_THREADS) dst[j] = acc[j];
}

// ---------------- Kernel E: reduce partials + bias ----------------
__global__ __launch_bounds__(256) void reduce_bias_kernel(
    const float* __restrict__ partials, const float* __restrict__ Pb,
    const int* __restrict__ bp, float* __restrict__ out, int n)
{
    const int i = blockIdx.x * 256 + threadIdx.x;
    if (i >= n) return;
    const int s = i >> SLICE_BITS;
    const int j = i & (SLICE_SIZE - 1);
    const float* p = partials + ((size_t)s * CHUNKS) * SLICE_SIZE + j;
    float sum = 0.0f;
#pragma unroll
    for (int g = 0; g < CHUNKS; ++g) sum += p[(size_t)g * SLICE_SIZE];
    out[i] = sum + Pb[bp[i]];
}

// ---------------- fallback: R3 slice-scan (3-stream) ----------------
#define FB_BATCH 4
__global__ __launch_bounds__(SCAN_THREADS, 1) void slice_scan_kernel(
    const float* __restrict__ x, const float* __restrict__ PW, int nparams,
    const int4* __restrict__ rows4, const int4* __restrict__ cols4,
    const int4* __restrict__ params4, float* __restrict__ partials,
    int e4_per_chunk)
{
    __shared__ float acc[SLICE_SIZE];
    __shared__ float pw_lds[NPARAMS_MAX];
    const int bid = blockIdx.x;
    const int s = bid / CHUNKS;
    const int c = bid % CHUNKS;
    for (int j = threadIdx.x; j < SLICE_SIZE; j += SCAN_THREADS) acc[j] = 0.0f;
    for (int j = threadIdx.x; j < nparams; j += SCAN_THREADS) pw_lds[j] = PW[j];
    __syncthreads();
    const int4* rp = rows4   + (size_t)c * e4_per_chunk;
    const int4* cp = cols4   + (size_t)c * e4_per_chunk;
    const int4* qp = params4 + (size_t)c * e4_per_chunk;
    const int per_thread = e4_per_chunk / SCAN_THREADS;
    for (int base = 0; base < per_thread; base += FB_BATCH) {
        int4 r[FB_BATCH], cc[FB_BATCH], pp[FB_BATCH];
#pragma unroll
        for (int b = 0; b < FB_BATCH; ++b) {
            const int g = (base + b) * SCAN_THREADS + threadIdx.x;
            r[b] = rp[g]; cc[b] = cp[g]; pp[b] = qp[g];
        }
#pragma unroll
        for (int b = 0; b < FB_BATCH; ++b) {
            if ((r[b].x >> SLICE_BITS) == s)
                atomicAdd(&acc[r[b].x & (SLICE_SIZE - 1)], pw_lds[pp[b].x] * x[cc[b].x]);
            if ((r[b].y >> SLICE_BITS) == s)
                atomicAdd(&acc[r[b].y & (SLICE_SIZE - 1)], pw_lds[pp[b].y] * x[cc[b].y]);
            if ((r[b].z >> SLICE_BITS) == s)
                atomicAdd(&acc[r[b].z & (SLICE_SIZE - 1)], pw_lds[pp[b].z] * x[cc[b].z]);
            if ((r[b].w >> SLICE_BITS) == s)
                atomicAdd(&acc[r[b].w & (SLICE_SIZE - 1)], pw_lds[pp[b].w] * x[cc[b].w]);
        }
    }
    __syncthreads();
    float* dst = partials + (size_t)bid * SLICE_SIZE;
    for (int j = threadIdx.x; j < SLICE_SIZE; j += SCAN_THREADS) dst[j] = acc[j];
}

__global__ __launch_bounds__(256) void bias_init_kernel(const float* __restrict__ Pb,
                                                        const int* __restrict__ bp,
                                                        float* __restrict__ out, int n) {
    int i = blockIdx.x * 256 + threadIdx.x;
    if (i < n) out[i] = Pb[bp[i]];
}

__global__ __launch_bounds__(256) void edge_scatter_kernel(const float* __restrict__ x,
                                                           const float* __restrict__ PW,
                                                           const int* __restrict__ rows,
                                                           const int* __restrict__ cols,
                                                           const int* __restrict__ params,
                                                           float* __restrict__ out, int E) {
    int e = blockIdx.x * 256 + threadIdx.x;
    if (e < E) atomicAdd(out + rows[e], PW[params[e]] * x[cols[e]]);
}

extern "C" void kernel_launch(void* const* d_in, const int* in_sizes, int n_in,
                              void* d_out, int out_size, void* d_ws, size_t ws_size,
                              hipStream_t stream) {
    const float* x        = (const float*)d_in[0];
    const float* Param_W  = (const float*)d_in[1];
    const float* Param_b  = (const float*)d_in[2];
    const int*   w_rows   = (const int*)d_in[3];
    const int*   w_cols   = (const int*)d_in[4];
    const int*   w_params = (const int*)d_in[5];
    const int*   b_params = (const int*)d_in[6];
    float* out = (float*)d_out;

    const int N_  = in_sizes[0];   // 262144
    const int NP_ = in_sizes[1];   // 1280
    const int E_  = in_sizes[3];   // 16777216
    const int e4  = E_ / 4;

    const size_t partial_bytes = (size_t)SLICES * CHUNKS * SLICE_SIZE * sizeof(float); // 32 MiB
    const size_t vals_bytes    = (size_t)E_ * sizeof(float);                            // 64 MiB
    const bool shapes_ok = (N_ == SLICES * SLICE_SIZE) && (NP_ <= NPARAMS_MAX) &&
                           (E_ % (4 * 256 * VB) == 0) &&
                           (E_ % (4 * CHUNKS * SCAN_THREADS * 2 * SB4) == 0);

    if (shapes_ok && ws_size >= vals_bytes + partial_bytes) {
        float*  vals     = (float*)d_ws;
        float*  partials = (float*)((char*)d_ws + vals_bytes);
        const int e4_per_chunk = e4 / CHUNKS;   // 131072
        val_kernel<<<e4 / (256 * VB), 256, 0, stream>>>(
            x, Param_W, NP_, (const v4i*)w_cols, (const v4i*)w_params, (float4*)vals);
        scan4_kernel<<<SLICES * CHUNKS, SCAN_THREADS, 0, stream>>>(
            (const int4*)w_rows, (const float4*)vals, partials, e4_per_chunk);
        reduce_bias_kernel<<<(N_ + 255) / 256, 256, 0, stream>>>(
            partials, Param_b, b_params, out, N_);
    } else if ((N_ == SLICES * SLICE_SIZE) && (NP_ <= NPARAMS_MAX) &&
               (E_ % (4 * CHUNKS * SCAN_THREADS * FB_BATCH) == 0) &&
               ws_size >= partial_bytes) {
        float* partials = (float*)d_ws;
        const int e4_per_chunk = e4 / CHUNKS;
        slice_scan_kernel<<<SLICES * CHUNKS, SCAN_THREADS, 0, stream>>>(
            x, Param_W, NP_, (const int4*)w_rows, (const int4*)w_cols,
            (const int4*)w_params, partials, e4_per_chunk);
        reduce_bias_kernel<<<(N_ + 255) / 256, 256, 0, stream>>>(
            partials, Param_b, b_params, out, N_);
    } else {
        bias_init_kernel<<<(N_ + 255) / 256, 256, 0, stream>>>(Param_b, b_params, out, N_);
        edge_scatter_kernel<<<(E_ + 255) / 256, 256, 0, stream>>>(
            x, Param_W, w_rows, w_cols, w_params, out, E_);
    }
}

// Round 9
// 331.522 us; speedup vs baseline: 1.0685x; 1.0685x over previous
//
#include <hip/hip_runtime.h>

// out[i] = sum_{e: rows[e]==i} Param_W[params[e]] * x[cols[e]] + Param_b[b_params[i]]
// N = 262144, E = 16777216, NPARAMS = 1280, NB = 16.
//
// Measured HW model: LDS ds_add_f32 ~3.1 cyc per ACTIVE lane (R5/R6) -> scan
// floor ~85 us. R8: scan4=104 (ping-pong ok), val regressed 113 (nt LOADS bad,
// compiler serialized VB=8). R9: val back to VB=4 cached loads (R6's 88 us
// form) + NONTEMPORAL STORES on vals4 so the 67 MB store stream stops evicting
// the 1 MB x working set from L2 (theory: x-gathers were missing to L3/HBM).

#define SLICE_BITS  15
#define SLICE_SIZE  (1 << SLICE_BITS)   // 32768
#define SLICES      8
#define CHUNKS      32
#define NPARAMS_MAX 2048
#define SCAN_THREADS 1024
#define SB4         4                   // int4-groups per ping-pong buffer
#define VB          4                   // batched groups per val-kernel thread

typedef float v4f __attribute__((ext_vector_type(4)));

// ---------------- Kernel V: val precompute (streaming) ----------------
__global__ __launch_bounds__(256) void val_kernel(
    const float* __restrict__ x, const float* __restrict__ PW, int nparams,
    const int4* __restrict__ cols4, const int4* __restrict__ params4,
    v4f* __restrict__ vals4)
{
    __shared__ float pw[NPARAMS_MAX];
    for (int j = threadIdx.x; j < nparams; j += 256) pw[j] = PW[j];
    __syncthreads();
    const int base = blockIdx.x * (256 * VB) + threadIdx.x;
    int4 c[VB], p[VB];
#pragma unroll
    for (int k = 0; k < VB; ++k) {
        c[k] = cols4[base + k * 256];     // cached loads (nt loads regressed in R8)
        p[k] = params4[base + k * 256];
    }
#pragma unroll
    for (int k = 0; k < VB; ++k) {
        v4f v;
        v.x = pw[p[k].x] * x[c[k].x];
        v.y = pw[p[k].y] * x[c[k].y];
        v.z = pw[p[k].z] * x[c[k].z];
        v.w = pw[p[k].w] * x[c[k].w];
        // nontemporal: don't let the 67 MB val stream evict x (1 MB) from L2
        __builtin_nontemporal_store(v, &vals4[base + k * 256]);
    }
}

// ------- Kernel S: 2-stream scan, ping-pong prefetch + predicated adds -------
__global__ __launch_bounds__(SCAN_THREADS, 1) void scan4_kernel(
    const int4* __restrict__ rows4, const float4* __restrict__ vals4,
    float* __restrict__ partials, int e4_per_chunk)
{
    __shared__ float acc[SLICE_SIZE];    // 128 KiB -> 1 block/CU
    const int bid = blockIdx.x;
    const int s = bid / CHUNKS;          // slice
    const int c = bid % CHUNKS;          // chunk; bid%8 == c%8 -> the 8 readers of a
                                         // chunk co-locate on one XCD (round-robin)
    for (int j = threadIdx.x; j < SLICE_SIZE; j += SCAN_THREADS) acc[j] = 0.0f;
    __syncthreads();

    const int4*   rp = rows4 + (size_t)c * e4_per_chunk;
    const float4* vp = vals4 + (size_t)c * e4_per_chunk;
    const int per_thread = e4_per_chunk / SCAN_THREADS;   // 128

    int4   rA[SB4], rB[SB4];
    float4 vA[SB4], vB[SB4];

#define LOAD(dstR, dstV, b0)                                             \
    _Pragma("unroll")                                                    \
    for (int b = 0; b < SB4; ++b) {                                      \
        const int g = ((b0) + b) * SCAN_THREADS + threadIdx.x;           \
        dstR[b] = rp[g];                                                 \
        dstV[b] = vp[g];                                                 \
    }
#define PROC(rX, vX)                                                     \
    _Pragma("unroll")                                                    \
    for (int b = 0; b < SB4; ++b) {                                      \
        if ((rX[b].x >> SLICE_BITS) == s) atomicAdd(&acc[rX[b].x & (SLICE_SIZE - 1)], vX[b].x); \
        if ((rX[b].y >> SLICE_BITS) == s) atomicAdd(&acc[rX[b].y & (SLICE_SIZE - 1)], vX[b].y); \
        if ((rX[b].z >> SLICE_BITS) == s) atomicAdd(&acc[rX[b].z & (SLICE_SIZE - 1)], vX[b].z); \
        if ((rX[b].w >> SLICE_BITS) == s) atomicAdd(&acc[rX[b].w & (SLICE_SIZE - 1)], vX[b].w); \
    }

    LOAD(rA, vA, 0)
    for (int base = 0; base < per_thread; base += 2 * SB4) {
        LOAD(rB, vB, base + SB4)           // in flight while A's atomics issue
        PROC(rA, vA)
        if (base + 2 * SB4 < per_thread) {
            LOAD(rA, vA, base + 2 * SB4)   // in flight while B's atomics issue
        }
        PROC(rB, vB)
    }
#undef LOAD
#undef PROC
    __syncthreads();

    float* dst = partials + (size_t)bid * SLICE_SIZE;
    for (int j = threadIdx.x; j < SLICE_SIZE; j += SCAN_THREADS) dst[j] = acc[j];
}

// ---------------- Kernel E: reduce partials + bias ----------------
__global__ __launch_bounds__(256) void reduce_bias_kernel(
    const float* __restrict__ partials, const float* __restrict__ Pb,
    const int* __restrict__ bp, float* __restrict__ out, int n)
{
    const int i = blockIdx.x * 256 + threadIdx.x;
    if (i >= n) return;
    const int s = i >> SLICE_BITS;
    const int j = i & (SLICE_SIZE - 1);
    const float* p = partials + ((size_t)s * CHUNKS) * SLICE_SIZE + j;
    float sum = 0.0f;
#pragma unroll
    for (int g = 0; g < CHUNKS; ++g) sum += p[(size_t)g * SLICE_SIZE];
    out[i] = sum + Pb[bp[i]];
}

// ---------------- fallback: R3 slice-scan (3-stream) ----------------
#define FB_BATCH 4
__global__ __launch_bounds__(SCAN_THREADS, 1) void slice_scan_kernel(
    const float* __restrict__ x, const float* __restrict__ PW, int nparams,
    const int4* __restrict__ rows4, const int4* __restrict__ cols4,
    const int4* __restrict__ params4, float* __restrict__ partials,
    int e4_per_chunk)
{
    __shared__ float acc[SLICE_SIZE];
    __shared__ float pw_lds[NPARAMS_MAX];
    const int bid = blockIdx.x;
    const int s = bid / CHUNKS;
    const int c = bid % CHUNKS;
    for (int j = threadIdx.x; j < SLICE_SIZE; j += SCAN_THREADS) acc[j] = 0.0f;
    for (int j = threadIdx.x; j < nparams; j += SCAN_THREADS) pw_lds[j] = PW[j];
    __syncthreads();
    const int4* rp = rows4   + (size_t)c * e4_per_chunk;
    const int4* cp = cols4   + (size_t)c * e4_per_chunk;
    const int4* qp = params4 + (size_t)c * e4_per_chunk;
    const int per_thread = e4_per_chunk / SCAN_THREADS;
    for (int base = 0; base < per_thread; base += FB_BATCH) {
        int4 r[FB_BATCH], cc[FB_BATCH], pp[FB_BATCH];
#pragma unroll
        for (int b = 0; b < FB_BATCH; ++b) {
            const int g = (base + b) * SCAN_THREADS + threadIdx.x;
            r[b] = rp[g]; cc[b] = cp[g]; pp[b] = qp[g];
        }
#pragma unroll
        for (int b = 0; b < FB_BATCH; ++b) {
            if ((r[b].x >> SLICE_BITS) == s)
                atomicAdd(&acc[r[b].x & (SLICE_SIZE - 1)], pw_lds[pp[b].x] * x[cc[b].x]);
            if ((r[b].y >> SLICE_BITS) == s)
                atomicAdd(&acc[r[b].y & (SLICE_SIZE - 1)], pw_lds[pp[b].y] * x[cc[b].y]);
            if ((r[b].z >> SLICE_BITS) == s)
                atomicAdd(&acc[r[b].z & (SLICE_SIZE - 1)], pw_lds[pp[b].z] * x[cc[b].z]);
            if ((r[b].w >> SLICE_BITS) == s)
                atomicAdd(&acc[r[b].w & (SLICE_SIZE - 1)], pw_lds[pp[b].w] * x[cc[b].w]);
        }
    }
    __syncthreads();
    float* dst = partials + (size_t)bid * SLICE_SIZE;
    for (int j = threadIdx.x; j < SLICE_SIZE; j += SCAN_THREADS) dst[j] = acc[j];
}

__global__ __launch_bounds__(256) void bias_init_kernel(const float* __restrict__ Pb,
                                                        const int* __restrict__ bp,
                                                        float* __restrict__ out, int n) {
    int i = blockIdx.x * 256 + threadIdx.x;
    if (i < n) out[i] = Pb[bp[i]];
}

__global__ __launch_bounds__(256) void edge_scatter_kernel(const float* __restrict__ x,
                                                           const float* __restrict__ PW,
                                                           const int* __restrict__ rows,
                                                           const int* __restrict__ cols,
                                                           const int* __restrict__ params,
                                                           float* __restrict__ out, int E) {
    int e = blockIdx.x * 256 + threadIdx.x;
    if (e < E) atomicAdd(out + rows[e], PW[params[e]] * x[cols[e]]);
}

extern "C" void kernel_launch(void* const* d_in, const int* in_sizes, int n_in,
                              void* d_out, int out_size, void* d_ws, size_t ws_size,
                              hipStream_t stream) {
    const float* x        = (const float*)d_in[0];
    const float* Param_W  = (const float*)d_in[1];
    const float* Param_b  = (const float*)d_in[2];
    const int*   w_rows   = (const int*)d_in[3];
    const int*   w_cols   = (const int*)d_in[4];
    const int*   w_params = (const int*)d_in[5];
    const int*   b_params = (const int*)d_in[6];
    float* out = (float*)d_out;

    const int N_  = in_sizes[0];   // 262144
    const int NP_ = in_sizes[1];   // 1280
    const int E_  = in_sizes[3];   // 16777216
    const int e4  = E_ / 4;

    const size_t partial_bytes = (size_t)SLICES * CHUNKS * SLICE_SIZE * sizeof(float); // 32 MiB
    const size_t vals_bytes    = (size_t)E_ * sizeof(float);                            // 64 MiB
    const bool shapes_ok = (N_ == SLICES * SLICE_SIZE) && (NP_ <= NPARAMS_MAX) &&
                           (E_ % (4 * 256 * VB) == 0) &&
                           (E_ % (4 * CHUNKS * SCAN_THREADS * 2 * SB4) == 0);

    if (shapes_ok && ws_size >= vals_bytes + partial_bytes) {
        float*  vals     = (float*)d_ws;
        float*  partials = (float*)((char*)d_ws + vals_bytes);
        const int e4_per_chunk = e4 / CHUNKS;   // 131072
        val_kernel<<<e4 / (256 * VB), 256, 0, stream>>>(
            x, Param_W, NP_, (const int4*)w_cols, (const int4*)w_params, (v4f*)vals);
        scan4_kernel<<<SLICES * CHUNKS, SCAN_THREADS, 0, stream>>>(
            (const int4*)w_rows, (const float4*)vals, partials, e4_per_chunk);
        reduce_bias_kernel<<<(N_ + 255) / 256, 256, 0, stream>>>(
            partials, Param_b, b_params, out, N_);
    } else if ((N_ == SLICES * SLICE_SIZE) && (NP_ <= NPARAMS_MAX) &&
               (E_ % (4 * CHUNKS * SCAN_THREADS * FB_BATCH) == 0) &&
               ws_size >= partial_bytes) {
        float* partials = (float*)d_ws;
        const int e4_per_chunk = e4 / CHUNKS;
        slice_scan_kernel<<<SLICES * CHUNKS, SCAN_THREADS, 0, stream>>>(
            x, Param_W, NP_, (const int4*)w_rows, (const int4*)w_cols,
            (const int4*)w_params, partials, e4_per_chunk);
        reduce_bias_kernel<<<(N_ + 255) / 256, 256, 0, stream>>>(
            partials, Param_b, b_params, out, N_);
    } else {
        bias_init_kernel<<<(N_ + 255) / 256, 256, 0, stream>>>(Param_b, b_params, out, N_);
        edge_scatter_kernel<<<(E_ + 255) / 256, 256, 0, stream>>>(
            x, Param_W, w_rows, w_cols, w_params, out, E_);
    }
}